// Round 2
// baseline (97.541 us; speedup 1.0000x reference)
//
#include <hip/hip_runtime.h>
#include <hip/hip_bf16.h>
#include <cstdint>

// NT-Xent contrastive loss, B=4096, D=128, T=0.1.
// loss = sum_i [ log(sum_{j!=i} exp(s_ij)) - s_{i,partner(i)} ] * (B/2)
// s_ij = 10 * cos(n_i, n_j).  We store n * sqrt(10*log2e) in bf16 so the
// MFMA accumulator is directly the exp2 argument (s * log2e).

typedef __bf16 bf16x8 __attribute__((ext_vector_type(8)));
typedef __bf16 bf16x2 __attribute__((ext_vector_type(2)));
typedef float  f32x4  __attribute__((ext_vector_type(4)));

#define NROWS 8192
#define DIM   128
#define ALPHA 3.7982827f            /* sqrt(10 * log2(e)) */
#define LN2   0.6931471805599453f

// ---- async global->LDS, 16B per lane, wave-uniform LDS base ----
__device__ __forceinline__ void load_lds16(const void* g, void* l) {
    __builtin_amdgcn_global_load_lds(
        (const __attribute__((address_space(1))) unsigned int*)(uintptr_t)g,
        (__attribute__((address_space(3))) unsigned int*)(uintptr_t)l,
        16, 0, 0);
}

// K-chunk xor swizzle: element chunk c (=k>>3) of row r stored at
// chunk (c&8)|((c^r)&7).  Contiguous per row (global_load_lds compatible),
// fragment ds_read_b128 stays at the free 2-way bank aliasing.

// ---------------- Kernel A: normalize + scale + swizzle + zero out --------
__global__ __launch_bounds__(256) void norm_kernel(
    const float* __restrict__ out1, const float* __restrict__ out2,
    __bf16* __restrict__ nb, float* __restrict__ dout)
{
    const int t = threadIdx.x, lane = t & 63, wid = t >> 6;
    const int row = blockIdx.x * 4 + wid;
    const float* src = (row < 4096) ? (out1 + (size_t)row * DIM)
                                    : (out2 + (size_t)(row - 4096) * DIM);
    float2 v = ((const float2*)src)[lane];
    float ss = v.x * v.x + v.y * v.y;
    #pragma unroll
    for (int off = 1; off < 64; off <<= 1) ss += __shfl_xor(ss, off);
    const float s = rsqrtf(ss) * ALPHA;

    const int c  = lane >> 2;                      // chunk of element 2*lane
    const int cs = (c & 8) | ((c ^ row) & 7);
    const int idx = row * DIM + cs * 8 + ((2 * lane) & 7);
    bf16x2 w;
    w.x = (__bf16)(v.x * s);
    w.y = (__bf16)(v.y * s);
    *(bf16x2*)(nb + idx) = w;

    if (blockIdx.x == 0 && t == 0) dout[0] = 0.0f;
}

// ---------------- Kernel B: Gram + exp + per-row partial sums -------------
// grid (64, 8): block = rows [rb*128,+128) x cols [cb*1024,+1024).
// 4 waves in 2x2; each wave owns a 64x64 tile per 128-col iteration.
// Both A (staged once) and B (streamed per ct) live in LDS -> low VGPR
// pressure, no spill.  Partial row sums stored plain (no atomics) to
// rowsum[row*16 + slot], slot = cb*2 + colhalf.
__global__ __launch_bounds__(256) void simloss_main(
    const __bf16* __restrict__ nb, float* __restrict__ rowsum)
{
    __shared__ __bf16 Asm[128 * DIM];             // 32 KB
    __shared__ __bf16 Bsm[128 * DIM];             // 32 KB
    const int t = threadIdx.x, lane = t & 63, wid = t >> 6;
    const int quad = lane >> 4, l15 = lane & 15;
    const int rb = blockIdx.x, cb = blockIdx.y;
    const int rloc  = (wid & 1) * 64;             // wave's row base in A tile
    const int ncol0 = (wid >> 1) * 64;            // wave's col base in B tile

    // swizzled chunk offsets per k-step (lane&7 == local row&7 for A and B)
    int cso[4];
    #pragma unroll
    for (int k = 0; k < 4; ++k) {
        int c = k * 4 + quad;
        cso[k] = ((c & 8) | ((c ^ lane) & 7)) * 8;
    }

    // stage A once: 128 rows x 256 B, contiguous
    {
        const char* gA = (const char*)(nb + (size_t)rb * 128 * DIM) + wid * 1024 + lane * 16;
        char* lA = (char*)Asm + wid * 1024;
        #pragma unroll
        for (int i = 0; i < 8; ++i) load_lds16(gA + i * 4096, lA + i * 4096);
    }

    float rowpart[4][4] = {};

    for (int ct = 0; ct < 8; ++ct) {
        __syncthreads();                           // Bsm free (also drains A on ct=0)
        const char* gB = (const char*)(nb + (size_t)(cb * 1024 + ct * 128) * DIM)
                         + wid * 1024 + lane * 16;
        char* lB = (char*)Bsm + wid * 1024;
        #pragma unroll
        for (int i = 0; i < 8; ++i) load_lds16(gB + i * 4096, lB + i * 4096);
        __syncthreads();                           // staging complete

        f32x4 acc[4][4] = {};
        #pragma unroll
        for (int k = 0; k < 4; ++k) {
            bf16x8 a[4], b[4];
            #pragma unroll
            for (int mt = 0; mt < 4; ++mt)
                a[mt] = *(const bf16x8*)(Asm + (rloc + mt * 16 + l15) * DIM + cso[k]);
            #pragma unroll
            for (int nt = 0; nt < 4; ++nt)
                b[nt] = *(const bf16x8*)(Bsm + (ncol0 + nt * 16 + l15) * DIM + cso[k]);
            #pragma unroll
            for (int mt = 0; mt < 4; ++mt)
                #pragma unroll
                for (int nt = 0; nt < 4; ++nt)
                    acc[mt][nt] = __builtin_amdgcn_mfma_f32_16x16x32_bf16(
                        a[mt], b[nt], acc[mt][nt], 0, 0, 0);
        }

        // acc is already s*log2e -> single v_exp_f32 each
        #pragma unroll
        for (int mt = 0; mt < 4; ++mt)
            #pragma unroll
            for (int nt = 0; nt < 4; ++nt)
                #pragma unroll
                for (int r = 0; r < 4; ++r)
                    rowpart[mt][r] += __builtin_amdgcn_exp2f(acc[mt][nt][r]);
    }

    // reduce 16 lanes sharing the cols; plain store, no atomics
    const int slot = cb * 2 + (wid >> 1);          // 16 partials per row
    #pragma unroll
    for (int mt = 0; mt < 4; ++mt)
        #pragma unroll
        for (int r = 0; r < 4; ++r) {
            float v = rowpart[mt][r];
            v += __shfl_xor(v, 1);
            v += __shfl_xor(v, 2);
            v += __shfl_xor(v, 4);
            v += __shfl_xor(v, 8);
            if (l15 == 0) {
                int grow = rb * 128 + rloc + mt * 16 + quad * 4 + r;
                rowsum[grow * 16 + slot] = v;
            }
        }
}

// ---------------- Kernel C: subtract diag, logs, positive pairs, reduce ----
__global__ __launch_bounds__(256) void finalize_kernel(
    const __bf16* __restrict__ nb, const float* __restrict__ rowsum,
    float* __restrict__ dout)
{
    const int t = threadIdx.x, lane = t & 63, wid = t >> 6;
    const int w = blockIdx.x * 4 + wid;            // 1024 waves, 8 rows each
    float wacc = 0.0f;
    for (int rr = 0; rr < 8; ++rr) {
        const int i = w * 8 + rr;
        const int p = i ^ 4096;                    // partner row
        // rows i and p share (row&7) so the k-swizzle cancels in the dot
        bf16x2 av = *(const bf16x2*)(nb + (size_t)i * DIM + 2 * lane);
        bf16x2 bv = *(const bf16x2*)(nb + (size_t)p * DIM + 2 * lane);
        float ax = (float)av.x, ay = (float)av.y;
        float bx = (float)bv.x, by = (float)bv.y;
        float self = ax * ax + ay * ay;            // diag arg, exactly as MFMA saw it
        float pos  = ax * bx + ay * by;            // s_pos * log2e
        float se   = (lane < 16) ? rowsum[(size_t)i * 16 + lane] : 0.0f;
        #pragma unroll
        for (int off = 1; off < 64; off <<= 1) {
            self += __shfl_xor(self, off);
            pos  += __shfl_xor(pos, off);
            se   += __shfl_xor(se, off);
        }
        if (lane == 0)
            wacc += logf(se - __builtin_amdgcn_exp2f(self)) - pos * LN2;
    }
    if (lane == 0) atomicAdd(dout, wacc * 2048.0f); // * B/2
}

extern "C" void kernel_launch(void* const* d_in, const int* in_sizes, int n_in,
                              void* d_out, int out_size, void* d_ws, size_t ws_size,
                              hipStream_t stream)
{
    const float* out1 = (const float*)d_in[0];
    const float* out2 = (const float*)d_in[1];
    __bf16* nb     = (__bf16*)d_ws;                                   // 2 MB
    float*  rowsum = (float*)((char*)d_ws + (size_t)NROWS * DIM * 2); // 512 KB
    float*  dout   = (float*)d_out;

    hipLaunchKernelGGL(norm_kernel, dim3(2048), dim3(256), 0, stream,
                       out1, out2, nb, dout);
    hipLaunchKernelGGL(simloss_main, dim3(64, 8), dim3(256), 0, stream,
                       (const __bf16*)nb, rowsum);
    hipLaunchKernelGGL(finalize_kernel, dim3(256), dim3(256), 0, stream,
                       (const __bf16*)nb, rowsum, dout);
}

// Round 3
// 95.938 us; speedup vs baseline: 1.0167x; 1.0167x over previous
//
#include <hip/hip_runtime.h>
#include <hip/hip_bf16.h>
#include <cstdint>

// NT-Xent contrastive loss, B=4096, D=128, T=0.1.
// loss = sum_i [ log(sum_{j!=i} exp(s_ij)) - s_{i,partner(i)} ] * (B/2)
// s_ij = 10 * cos(n_i, n_j).  We store n * sqrt(10*log2e) in bf16 so the
// MFMA accumulator is directly the exp2 argument (s * log2e).

typedef __bf16 bf16x8 __attribute__((ext_vector_type(8)));
typedef __bf16 bf16x2 __attribute__((ext_vector_type(2)));
typedef float  f32x4  __attribute__((ext_vector_type(4)));

#define NROWS 8192
#define DIM   128
#define ALPHA 3.7982827f            /* sqrt(10 * log2(e)) */
#define LN2   0.6931471805599453f

// ---- async global->LDS, 16B per lane, wave-uniform LDS base ----
__device__ __forceinline__ void load_lds16(const void* g, void* l) {
    __builtin_amdgcn_global_load_lds(
        (const __attribute__((address_space(1))) unsigned int*)(uintptr_t)g,
        (__attribute__((address_space(3))) unsigned int*)(uintptr_t)l,
        16, 0, 0);
}

// K-chunk xor swizzle: element chunk c (=k>>3) of row r stored at
// chunk (c&8)|((c^r)&7).  Contiguous per row (global_load_lds compatible),
// fragment ds_read_b128 stays at the free 2-way bank aliasing.

// ---------------- Kernel A: normalize + scale + swizzle + zero out --------
__global__ __launch_bounds__(256) void norm_kernel(
    const float* __restrict__ out1, const float* __restrict__ out2,
    __bf16* __restrict__ nb, float* __restrict__ dout)
{
    const int t = threadIdx.x, lane = t & 63, wid = t >> 6;
    const int row = blockIdx.x * 4 + wid;
    const float* src = (row < 4096) ? (out1 + (size_t)row * DIM)
                                    : (out2 + (size_t)(row - 4096) * DIM);
    float2 v = ((const float2*)src)[lane];
    float ss = v.x * v.x + v.y * v.y;
    #pragma unroll
    for (int off = 1; off < 64; off <<= 1) ss += __shfl_xor(ss, off);
    const float s = rsqrtf(ss) * ALPHA;

    const int c  = lane >> 2;                      // chunk of element 2*lane
    const int cs = (c & 8) | ((c ^ row) & 7);
    const int idx = row * DIM + cs * 8 + ((2 * lane) & 7);
    bf16x2 w;
    w.x = (__bf16)(v.x * s);
    w.y = (__bf16)(v.y * s);
    *(bf16x2*)(nb + idx) = w;

    if (blockIdx.x == 0 && t == 0) dout[0] = 0.0f;
}

// ---------------- Kernel B: Gram + exp + per-row partial sums -------------
// grid (64, 8): block = rows [rb*128,+128) x cols [cb*1024,+1024).
// 4 waves in 2x2; each wave owns a 64x64 tile per 128-col iteration.
// A-strip fragments REGISTER-resident (K=128 fits in 64 VGPRs; ~180 live
// regs, no spill at launch_bounds(256,2)).  Only B streams through LDS
// (32 KB single buffer) -> 16 ds_read_b128 per ct per wave, half of the
// R2 A+B-in-LDS variant.  Partial row sums stored plain (no atomics) to
// rowsum[row*16 + slot], slot = cb*2 + colhalf.
__global__ __launch_bounds__(256, 2) void simloss_main(
    const __bf16* __restrict__ nb, float* __restrict__ rowsum)
{
    __shared__ __bf16 Bsm[128 * DIM];             // 32 KB
    const int t = threadIdx.x, lane = t & 63, wid = t >> 6;
    const int quad = lane >> 4, l15 = lane & 15;
    const int rb = blockIdx.x, cb = blockIdx.y;
    const int rowbase = rb * 128 + (wid & 1) * 64;   // global row of wave tile
    const int ncol0   = (wid >> 1) * 64;             // col offset inside B tile

    // swizzled chunk offsets per k-step (lane&7 == row&7 for both A and B)
    int cso[4];
    #pragma unroll
    for (int k = 0; k < 4; ++k) {
        int c = k * 4 + quad;
        cso[k] = ((c & 8) | ((c ^ lane) & 7)) * 8;
    }

    // A fragments from global (L2-hot), 16 x 16B per lane
    bf16x8 afrag[4][4];
    #pragma unroll
    for (int mt = 0; mt < 4; ++mt) {
        const __bf16* ar = nb + (size_t)(rowbase + mt * 16 + l15) * DIM;
        #pragma unroll
        for (int k = 0; k < 4; ++k) afrag[mt][k] = *(const bf16x8*)(ar + cso[k]);
    }

    float rowpart[4][4] = {};

    for (int ct = 0; ct < 8; ++ct) {
        __syncthreads();                           // Bsm free
        const char* gB = (const char*)(nb + (size_t)(cb * 1024 + ct * 128) * DIM)
                         + wid * 1024 + lane * 16;
        char* lB = (char*)Bsm + wid * 1024;
        #pragma unroll
        for (int i = 0; i < 8; ++i) load_lds16(gB + i * 4096, lB + i * 4096);
        __syncthreads();                           // staging complete

        f32x4 acc[4][4] = {};
        #pragma unroll
        for (int k = 0; k < 4; ++k) {
            bf16x8 b[4];
            #pragma unroll
            for (int nt = 0; nt < 4; ++nt)
                b[nt] = *(const bf16x8*)(Bsm + (ncol0 + nt * 16 + l15) * DIM + cso[k]);
            #pragma unroll
            for (int mt = 0; mt < 4; ++mt)
                #pragma unroll
                for (int nt = 0; nt < 4; ++nt)
                    acc[mt][nt] = __builtin_amdgcn_mfma_f32_16x16x32_bf16(
                        afrag[mt][k], b[nt], acc[mt][nt], 0, 0, 0);
        }

        // acc is already s*log2e -> single v_exp_f32 each
        #pragma unroll
        for (int mt = 0; mt < 4; ++mt)
            #pragma unroll
            for (int nt = 0; nt < 4; ++nt)
                #pragma unroll
                for (int r = 0; r < 4; ++r)
                    rowpart[mt][r] += __builtin_amdgcn_exp2f(acc[mt][nt][r]);
    }

    // reduce 16 lanes sharing the cols; plain store, no atomics
    const int slot = cb * 2 + (wid >> 1);          // 16 partials per row
    #pragma unroll
    for (int mt = 0; mt < 4; ++mt)
        #pragma unroll
        for (int r = 0; r < 4; ++r) {
            float v = rowpart[mt][r];
            v += __shfl_xor(v, 1);
            v += __shfl_xor(v, 2);
            v += __shfl_xor(v, 4);
            v += __shfl_xor(v, 8);
            if (l15 == 0) {
                int grow = rowbase + mt * 16 + quad * 4 + r;
                rowsum[grow * 16 + slot] = v;
            }
        }
}

// ---------------- Kernel C: subtract diag, logs, positive pairs, reduce ----
__global__ __launch_bounds__(256) void finalize_kernel(
    const __bf16* __restrict__ nb, const float* __restrict__ rowsum,
    float* __restrict__ dout)
{
    const int t = threadIdx.x, lane = t & 63, wid = t >> 6;
    const int w = blockIdx.x * 4 + wid;            // 1024 waves, 8 rows each
    float wacc = 0.0f;
    for (int rr = 0; rr < 8; ++rr) {
        const int i = w * 8 + rr;
        const int p = i ^ 4096;                    // partner row
        // rows i and p share (row&7) so the k-swizzle cancels in the dot
        bf16x2 av = *(const bf16x2*)(nb + (size_t)i * DIM + 2 * lane);
        bf16x2 bv = *(const bf16x2*)(nb + (size_t)p * DIM + 2 * lane);
        float ax = (float)av.x, ay = (float)av.y;
        float bx = (float)bv.x, by = (float)bv.y;
        float self = ax * ax + ay * ay;            // diag arg, exactly as MFMA saw it
        float pos  = ax * bx + ay * by;            // s_pos * log2e
        float se   = (lane < 16) ? rowsum[(size_t)i * 16 + lane] : 0.0f;
        #pragma unroll
        for (int off = 1; off < 64; off <<= 1) {
            self += __shfl_xor(self, off);
            pos  += __shfl_xor(pos, off);
            se   += __shfl_xor(se, off);
        }
        if (lane == 0)
            wacc += logf(se - __builtin_amdgcn_exp2f(self)) - pos * LN2;
    }
    if (lane == 0) atomicAdd(dout, wacc * 2048.0f); // * B/2
}

extern "C" void kernel_launch(void* const* d_in, const int* in_sizes, int n_in,
                              void* d_out, int out_size, void* d_ws, size_t ws_size,
                              hipStream_t stream)
{
    const float* out1 = (const float*)d_in[0];
    const float* out2 = (const float*)d_in[1];
    __bf16* nb     = (__bf16*)d_ws;                                   // 2 MB
    float*  rowsum = (float*)((char*)d_ws + (size_t)NROWS * DIM * 2); // 512 KB
    float*  dout   = (float*)d_out;

    hipLaunchKernelGGL(norm_kernel, dim3(2048), dim3(256), 0, stream,
                       out1, out2, nb, dout);
    hipLaunchKernelGGL(simloss_main, dim3(64, 8), dim3(256), 0, stream,
                       (const __bf16*)nb, rowsum);
    hipLaunchKernelGGL(finalize_kernel, dim3(256), dim3(256), 0, stream,
                       (const __bf16*)nb, rowsum, dout);
}